// Round 6
// baseline (44.765 us; speedup 1.0000x reference)
//
#include <hip/hip_runtime.h>
#include <math.h>

#define SM1 2047.0f
#define CHUNK 64
#define NCHUNK 32

// ws float-index layout:
//   0      : poles[32]
//   32     : d[32]            d = exp(-p/2047)
//   64     : dW1[32]          d^(W+1)
//   96     : pf[32]           spectral filter
//   128    : (int) W
//   256    : wsum[32][32]     [k*32+o]
//   2048   : xmean partials [64 blocks][32 c]
//   4096   : xsum[8][2048]    (16384)
//   20480  : CF[8][32][32]    carry-in fwd  [b][k][chunk]
//   28672  : CB[8][32][32]    carry-in bwd
//   36864  : zF[8][2048][32]  chunk-local fwd scan (524288)
//   561152 : zB[8][2048][32]  chunk-local bwd scan (524288)

// K1: xsum + per-block channel partials. Reads x exactly once.
__global__ void k1(const float* __restrict__ x, float* __restrict__ ws) {
    int blk = blockIdx.x;                 // 64 blocks: b = blk>>3, s-tile = blk&7
    int b = blk >> 3;
    int s = ((blk & 7) << 8) + threadIdx.x;
    __shared__ float pr[32][4];
    int lane = threadIdx.x & 63, wid = threadIdx.x >> 6;
    float acc = 0.f;
#pragma unroll
    for (int c = 0; c < 32; ++c) {
        float v = x[(size_t)((b << 5) + c) * 2048 + s];
        acc += v;
        float r = v;
        for (int off = 32; off; off >>= 1) r += __shfl_xor(r, off);
        if (lane == 0) pr[c][wid] = r;
    }
    ws[4096 + (b << 11) + s] = acc;       // xsum
    __syncthreads();
    if (threadIdx.x < 32) {
        float m = pr[threadIdx.x][0] + pr[threadIdx.x][1] + pr[threadIdx.x][2] + pr[threadIdx.x][3];
        ws[2048 + (blk << 5) + threadIdx.x] = m;
    }
}

// K2: xmean reduce + pole prep + wsum, one block.
__global__ void k2(const float* __restrict__ c_star, const float* __restrict__ dt,
                   const float* __restrict__ log_poles, const float* __restrict__ pole_w,
                   const float* __restrict__ pole_b,
                   const float* __restrict__ wla, const float* __restrict__ wph,
                   float* __restrict__ ws) {
    __shared__ float xm[32];
    int tid = threadIdx.x;
    if (tid < 32) {
        float m = 0.f;
        for (int blk = 0; blk < 64; ++blk) m += ws[2048 + (blk << 5) + tid];
        xm[tid] = m * (1.0f / (8.0f * 2048.0f));
    }
    __syncthreads();
    if (tid < 32) {
        int k = tid;
        float mc = c_star[0];
        for (int b = 1; b < 8; ++b) mc = fmaxf(mc, c_star[b]);
        float mdn = mc * dt[0];                      // CAUSAL_SAFETY = 1
        int W = (int)(mdn * SM1);
        while (W + 1 <= 2047 && (float)(W + 1) / SM1 <= mdn) ++W;
        while (W > 0 && (float)W / SM1 > mdn) --W;
        W = min(max(W, 0), 2047);
        if (k == 0) ((int*)ws)[128] = W;
        float acc = pole_b[k];
        for (int c = 0; c < 32; ++c) acc += xm[c] * pole_w[(c << 5) + k];
        float z = log_poles[k] + 0.1f * tanhf(acc);  // POLE_OFF_SCALE
        float p = log1pf(expf(z));                   // softplus
        p = fminf(fmaxf(p, 0.1f), 100.0f);
        ws[k] = p;
        ws[32 + k] = expf(-p / SM1);
        ws[64 + k] = expf(-p * (float)(W + 1) / SM1);
        float kn = (float)k / 31.0f;
        ws[96 + k] = expf(-4.0f * kn * kn);          // FILTER_STRENGTH
    }
    // wsum[k][o] = sum_c sigmoid(wla)*cos(wph)
    int k = tid >> 5, o = tid & 31;
    float a = 0.f;
#pragma unroll 4
    for (int c = 0; c < 32; ++c) {
        int e = ((k << 5) + c) * 32 + o;
        float amp = 1.0f / (1.0f + expf(-wla[e]));
        a += amp * cosf(wph[e]);
    }
    ws[256 + tid] = a;
}

// K3: per-(b,dir) block: chunk-local scans + in-block weighted carry scan.
__global__ void k3(float* __restrict__ ws) {
    __shared__ float xr[2048];
    __shared__ float carr[NCHUNK][33];
    __shared__ float psh[32], dsh[32], dwsh[32];
    int tid = threadIdx.x;
    int b = blockIdx.x >> 1, dir = blockIdx.x & 1;
    for (int i = tid; i < 2048; i += 1024) xr[i] = ws[4096 + (b << 11) + i];
    if (tid < 32) { psh[tid] = ws[tid]; dsh[tid] = ws[32 + tid]; dwsh[tid] = ws[64 + tid]; }
    __syncthreads();
    int chunk = tid >> 5, k = tid & 31;
    int W = ((const int*)ws)[128];
    float d = dsh[k], dw = dwsh[k];
    float st = 0.f;
    float* z = ws + ((dir == 0) ? 36864 : 561152) + (((size_t)b << 11) << 5) + k;
    if (dir == 0) {
        int t0 = chunk << 6;
#pragma unroll 4
        for (int i = 0; i < CHUNK; ++i) {
            int t = t0 + i;
            float u = xr[t];
            int tl = t - W - 1;
            if (tl >= 0) u = fmaf(-dw, xr[tl], u);
            st = fmaf(d, st, u);
            z[t << 5] = st;
        }
    } else {
        int t1 = (chunk << 6) + 63;
#pragma unroll 4
        for (int i = 0; i < CHUNK; ++i) {
            int t = t1 - i;
            float u = xr[t];
            int th = t + W + 1;
            if (th <= 2047) u = fmaf(-dw, xr[th], u);
            st = fmaf(d, st, u);
            z[t << 5] = st;
        }
    }
    int sidx = (dir == 0) ? chunk : (NCHUNK - 1 - chunk);
    carr[sidx][k] = st;
    // weighted inclusive Hillis-Steele over sidx: T_s = loc_s + dL * T_{s-1}
    float m = expf(-psh[k] * (float)CHUNK / SM1);    // dL = d^CHUNK
    float cur = st;
    for (int off = 1; off < NCHUNK; off <<= 1) {
        __syncthreads();
        float prev = (sidx >= off) ? carr[sidx - off][k] : 0.f;
        __syncthreads();
        cur = fmaf(m, prev, cur);
        carr[sidx][k] = cur;
        m = m * m;
    }
    __syncthreads();
    float cin = (sidx == 0) ? 0.f : carr[sidx - 1][k];   // exclusive = carry-in
    ws[((dir == 0) ? 20480 : 28672) + (((b << 5) + k) << 5) + chunk] = cin;
}

// K4: carry fixup + inline scale + 32x32 mix + coalesced store.
__global__ void k4(const float* __restrict__ ws, float* __restrict__ out) {
    __shared__ float wl[1024];
    __shared__ float yt[32 * 33];
    __shared__ float psh[32], dsh[32], pfsh[32], cf[32], cb[32];
    int tid = threadIdx.x;
    int b = blockIdx.x >> 6;
    int t0 = (blockIdx.x & 63) << 5;   // 32 t per block, within one chunk
    int c0 = t0 >> 6;
    wl[tid] = ws[256 + tid];
    if (tid < 32) {
        psh[tid] = ws[tid]; dsh[tid] = ws[32 + tid]; pfsh[tid] = ws[96 + tid];
        cf[tid] = ws[20480 + (((b << 5) + tid) << 5) + c0];
        cb[tid] = ws[28672 + (((b << 5) + tid) << 5) + c0];
    }
    __syncthreads();
    int W = ((const int*)ws)[128];
    {
        int tt = tid >> 5, k = tid & 31;
        int t = t0 + tt;
        int i = t & 63;
        float p = psh[k], d = dsh[k];
        float zf = ws[36864 + (size_t)(((b << 11) + t) << 5) + k];
        float zb = ws[561152 + (size_t)(((b << 11) + t) << 5) + k];
        float pw1 = expf(-p * (float)(i + 1) / SM1);       // d^(i+1)
        float pw2 = expf(-p * (float)(CHUNK - i) / SM1);   // d^(L-i)
        float v = zf + pw1 * cf[k] + zb + pw2 * cb[k] - ws[4096 + (b << 11) + t];
        float den = -expm1f(-p / SM1);                     // 1-d
        int n1 = min(W, t), n2 = min(W, 2047 - t);
        float g1 = d * (-expm1f(-p * (float)n1 / SM1)) / den;
        float g2 = d * (-expm1f(-p * (float)n2 / SM1)) / den;
        yt[tt * 33 + k] = v * (pfsh[k] / (1.0f + g1 + g2));
    }
    __syncthreads();
    {
        int o = tid >> 5, tt = tid & 31;
        float acc = 0.f;
#pragma unroll
        for (int k = 0; k < 32; ++k) acc = fmaf(yt[tt * 33 + k], wl[(k << 5) + o], acc);
        out[(size_t)((b << 5) + o) * 2048 + t0 + tt] = acc;
    }
}

extern "C" void kernel_launch(void* const* d_in, const int* in_sizes, int n_in,
                              void* d_out, int out_size, void* d_ws, size_t ws_size,
                              hipStream_t stream) {
    const float* x      = (const float*)d_in[0];
    const float* c_star = (const float*)d_in[1];
    const float* dt     = (const float*)d_in[2];
    // d_in[3] = dx_star (unused)
    const float* wla    = (const float*)d_in[4];
    const float* wph    = (const float*)d_in[5];
    const float* lp     = (const float*)d_in[6];
    const float* pw     = (const float*)d_in[7];
    const float* pb     = (const float*)d_in[8];
    float* out = (float*)d_out;
    float* ws  = (float*)d_ws;

    k1<<<64,  256,  0, stream>>>(x, ws);
    k2<<<1,   1024, 0, stream>>>(c_star, dt, lp, pw, pb, wla, wph, ws);
    k3<<<16,  1024, 0, stream>>>(ws);
    k4<<<512, 1024, 0, stream>>>(ws, out);
}